// Round 1
// baseline (310.857 us; speedup 1.0000x reference)
//
#include <hip/hip_runtime.h>
#include <math.h>

// MambaBlock, fp32 in/out, bf16 MFMA compute.
// uv = x @ Wi^T + bi ; u,v = split(uv) ; y = silu(dwconv3(v)+bc)*u ; out = y @ Wo^T + bo
// B=4, L=4096, D=1024 -> M = 16384 rows; GEMM1 N=2048, GEMM2 N=1024, K=1024.
//
// ws layout (bf16 shorts): uv[16384][2048] | xb[16384][1024] (reused as yb) |
// Wib[2048][1024] | Wob[1024][1024]  = 102 MiB total.
//
// GEMM v2: 256x256 tile, BK=32, 512 threads (8 waves, 2M x 4N), 4-slot LDS
// ring buffer (128 KiB), prefetch depth 3 K-tiles, counted s_waitcnt vmcnt
// (never 0 in the main loop) + raw s_barrier.  T3+T4 per the 256^2 template:
// the old 128^2 structure drained vmcnt(0) every K-step and ceilings at
// ~890 TF; here loads for tile t get 3 tiles of MFMA to land.
//
// LDS swizzle (64B rows, 4x16B groups): logical group g of row r stored at
// physical g ^ ((r>>1)&3).  Staging pre-swizzles the GLOBAL source address
// (global_load_lds dest must stay linear); ds_read applies the same XOR.
// Bank slots: (r&1)*16 + pg*4 -> 8 distinct slots per 16-lane group -> 2-way
// aliasing (free per m136).

typedef __attribute__((ext_vector_type(8))) short short8;
typedef __attribute__((ext_vector_type(4))) float floatx4;

__device__ __forceinline__ float b2f(short s) {
    unsigned int u = ((unsigned int)(unsigned short)s) << 16;
    float f;
    __builtin_memcpy(&f, &u, 4);
    return f;
}

__device__ __forceinline__ short f2b(float f) {
    unsigned int u;
    __builtin_memcpy(&u, &f, 4);
    u += 0x7fffu + ((u >> 16) & 1u);   // round-to-nearest-even
    return (short)(u >> 16);
}

// async 16B/lane global->LDS; LDS dest = wave-uniform base + lane*16B.
__device__ __forceinline__ void gl_lds16(const short* g, short* l) {
    __builtin_amdgcn_global_load_lds(
        (const __attribute__((address_space(1))) unsigned int*)g,
        (__attribute__((address_space(3))) unsigned int*)l,
        16, 0, 0);
}

// single fp32->bf16 conversion pass over x, Wi, Wo (8 elems/thread)
__global__ __launch_bounds__(256) void cvt_all(
    const float* __restrict__ x, const float* __restrict__ Wi,
    const float* __restrict__ Wo, short* __restrict__ xb,
    short* __restrict__ Wib, short* __restrict__ Wob)
{
    constexpr int n1 = 16384 * 1024 / 8;
    constexpr int n2 = 2048 * 1024 / 8;
    constexpr int n3 = 1024 * 1024 / 8;
    int i = blockIdx.x * 256 + threadIdx.x;
    const float* src;
    short* dst;
    int j;
    if (i < n1)           { src = x;  dst = xb;  j = i; }
    else if (i < n1 + n2) { src = Wi; dst = Wib; j = i - n1; }
    else if (i < n1 + n2 + n3) { src = Wo; dst = Wob; j = i - n1 - n2; }
    else return;
    float4 a = ((const float4*)src)[2 * j];
    float4 b = ((const float4*)src)[2 * j + 1];
    short8 o;
    o[0] = f2b(a.x); o[1] = f2b(a.y); o[2] = f2b(a.z); o[3] = f2b(a.w);
    o[4] = f2b(b.x); o[5] = f2b(b.y); o[6] = f2b(b.z); o[7] = f2b(b.w);
    ((short8*)dst)[j] = o;
}

// C[m][n] = sum_k A[m][k]*B[n][k] + bias[n].  A,B bf16 (B row-major [N][K]).
// OUTF32: C fp32, else C bf16.  256x256 tile, BK=32, deep-pipelined.
template <bool OUTF32>
__global__ __launch_bounds__(512, 2) void gemm_bt(
    const short* __restrict__ A, const short* __restrict__ B,
    const float* __restrict__ bias, void* __restrict__ Cv,
    int lda, int ldb, int ldc)
{
    constexpr int K  = 1024;
    constexpr int NT = K / 32;                 // 32 K-tiles
    // 4-slot ring: slot = tile & 3.  Each slot: 256 rows x 32 shorts = 16 KB.
    __shared__ __attribute__((aligned(16))) short As[4 * 8192];
    __shared__ __attribute__((aligned(16))) short Bs[4 * 8192];

    const int tid  = threadIdx.x;
    const int wave = tid >> 6;                 // 0..7
    const int lane = tid & 63;
    const int mBase = blockIdx.y * 256;
    const int nBase = blockIdx.x * 256;

    floatx4 acc[8][4];
#pragma unroll
    for (int i = 0; i < 8; i++)
#pragma unroll
        for (int j = 0; j < 4; j++) acc[i][j] = {0.f, 0.f, 0.f, 0.f};

    // ---- staging: wave w owns rows [32w, 32w+32) of both A and B tiles.
    // Per tile: 2 instrs for A + 2 for B (each instr = 16 rows x 64B = 1KB).
    // lane -> row (lane>>2), dest 16B group (lane&3); source group is
    // dest ^ ((row>>1)&3)  (pre-swizzled global address, linear LDS dest).
    const int srow = lane >> 2;                // 0..15
    const int sg   = ((lane & 3) ^ ((srow >> 1) & 3)) * 8;
    const short* gA = A + (size_t)(mBase + wave * 32 + srow) * lda + sg;
    const short* gB = B + (size_t)(nBase + wave * 32 + srow) * ldb + sg;
    short* lA0 = &As[wave * 1024];             // rows 32w.. of slot 0
    short* lB0 = &Bs[wave * 1024];

    auto stage = [&](int kk, int slot) {
#pragma unroll
        for (int j = 0; j < 2; j++) {
            gl_lds16(gA + (size_t)(16 * j) * lda + kk, lA0 + slot * 8192 + j * 512);
            gl_lds16(gB + (size_t)(16 * j) * ldb + kk, lB0 + slot * 8192 + j * 512);
        }
    };

    // ---- fragment addressing: wave (wm = wave>>2, wn = wave&3) owns a
    // 128x64 C panel: 8 m-frags x 4 n-frags of 16x16.
    const int fRow = lane & 15;
    const int lg   = lane >> 4;                // k-group 0..3 (8 elems each)
    const int pg8  = (lg ^ ((fRow >> 1) & 3)) * 8;   // physical group offset
    const int mq   = (wave >> 2) * 128;
    const int nq   = (wave & 3) * 64;
    const int aBase = (mq + fRow) * 32 + pg8;
    const int bBase = (nq + fRow) * 32 + pg8;

    auto compute = [&](int slot) {
        const short* Ab = &As[slot * 8192];
        const short* Bb = &Bs[slot * 8192];
        short8 av[8], bv[4];
#pragma unroll
        for (int mi = 0; mi < 8; mi++)
            av[mi] = *(const short8*)&Ab[aBase + mi * 512];
#pragma unroll
        for (int ni = 0; ni < 4; ni++)
            bv[ni] = *(const short8*)&Bb[bBase + ni * 512];
        __builtin_amdgcn_s_setprio(1);
#pragma unroll
        for (int mi = 0; mi < 8; mi++)
#pragma unroll
            for (int ni = 0; ni < 4; ni++)
                acc[mi][ni] = __builtin_amdgcn_mfma_f32_16x16x32_bf16(
                    av[mi], bv[ni], acc[mi][ni], 0, 0, 0);
        __builtin_amdgcn_s_setprio(0);
    };

    // ---- prologue: 3 tiles in flight (12 loads/thread)
    stage(0, 0);
    stage(32, 1);
    stage(64, 2);

    // ---- main loop: stage tile t+3 into slot (t+3)&3 (= slot read at t-1,
    // freed by t-1's trailing barrier), then wait ONLY for tile t's loads
    // (12 = 3 tiles x 4 loads stay in flight).
    for (int t = 0; t < NT - 3; ++t) {
        stage((t + 3) * 32, (t + 3) & 3);
        asm volatile("s_waitcnt vmcnt(12)" ::: "memory");
        __builtin_amdgcn_s_barrier();          // all waves' tile-t loads landed
        asm volatile("" ::: "memory");
        compute(t & 3);
        asm volatile("" ::: "memory");
        __builtin_amdgcn_s_barrier();          // slot t&3 free for reuse
        asm volatile("" ::: "memory");
    }

    // ---- epilogue: drain tiles NT-3..NT-1 (no more staging)
    asm volatile("s_waitcnt vmcnt(8)" ::: "memory");
    __builtin_amdgcn_s_barrier();
    asm volatile("" ::: "memory");
    compute((NT - 3) & 3);
    __builtin_amdgcn_s_barrier();
    asm volatile("s_waitcnt vmcnt(4)" ::: "memory");
    __builtin_amdgcn_s_barrier();
    asm volatile("" ::: "memory");
    compute((NT - 2) & 3);
    __builtin_amdgcn_s_barrier();
    asm volatile("s_waitcnt vmcnt(0)" ::: "memory");
    __builtin_amdgcn_s_barrier();
    asm volatile("" ::: "memory");
    compute((NT - 1) & 3);

    // C/D layout: col = lane&15, row = (lane>>4)*4 + reg   [m89/m91-verified]
    const int colq = lane & 15;
    const int rowq = lg * 4;
#pragma unroll
    for (int ni = 0; ni < 4; ni++) {
        const int col = nBase + nq + ni * 16 + colq;
        const float bvv = bias[col];
#pragma unroll
        for (int mi = 0; mi < 8; mi++) {
            const int row = mBase + mq + mi * 16 + rowq;
#pragma unroll
            for (int r = 0; r < 4; r++) {
                float v = acc[mi][ni][r] + bvv;
                if (OUTF32)
                    ((float*)Cv)[(size_t)(row + r) * ldc + col] = v;
                else
                    ((short*)Cv)[(size_t)(row + r) * ldc + col] = f2b(v);
            }
        }
    }
}

// y[m][d] = silu( v[m-1]*w0 + v[m]*w1 + v[m+1]*w2 + bc ) * u[m][d]
// uv bf16 [16384][2048] (u cols 0..1023, v cols 1024..2047); Wc/bc fp32;
// y written bf16 to yb [16384][1024]. 8 channels per thread.
__global__ __launch_bounds__(256) void conv_gate(
    const short* __restrict__ uv, const float* __restrict__ Wc,
    const float* __restrict__ bc, short* __restrict__ yb)
{
    const int idx = blockIdx.x * 256 + threadIdx.x;
    const int d8 = idx & 127;
    const int m  = idx >> 7;
    const int l  = m & 4095;             // L = 4096, zero-pad at batch edges
    const int d  = d8 * 8;

    float w[24];
#pragma unroll
    for (int q = 0; q < 6; q++)
        *(float4*)&w[q * 4] = ((const float4*)(Wc + d * 3))[q];
    float bcv[8];
    *(float4*)&bcv[0] = ((const float4*)(bc + d))[0];
    *(float4*)&bcv[4] = ((const float4*)(bc + d))[1];

    const size_t rowu = (size_t)m * 2048 + d;
    const size_t rowv = rowu + 1024;

    const short8 z = {0, 0, 0, 0, 0, 0, 0, 0};
    const short8 us = *(const short8*)(uv + rowu);
    const short8 vc = *(const short8*)(uv + rowv);
    const short8 vm = (l > 0)    ? *(const short8*)(uv + rowv - 2048) : z;
    const short8 vp = (l < 4095) ? *(const short8*)(uv + rowv + 2048) : z;

    short8 outv;
#pragma unroll
    for (int j = 0; j < 8; j++) {
        float y = b2f(vm[j]) * w[j * 3 + 0]
                + b2f(vc[j]) * w[j * 3 + 1]
                + b2f(vp[j]) * w[j * 3 + 2]
                + bcv[j];
        float sil = y / (1.0f + expf(-y));
        outv[j] = f2b(sil * b2f(us[j]));
    }
    *(short8*)(yb + (size_t)m * 1024 + d) = outv;
}

extern "C" void kernel_launch(void* const* d_in, const int* in_sizes, int n_in,
                              void* d_out, int out_size, void* d_ws, size_t ws_size,
                              hipStream_t stream)
{
    const float* x  = (const float*)d_in[0];   // [4,4096,1024]
    const float* Wi = (const float*)d_in[1];   // [2048,1024]
    const float* bi = (const float*)d_in[2];   // [2048]
    const float* Wc = (const float*)d_in[3];   // [1024,1,3]
    const float* bc = (const float*)d_in[4];   // [1024]
    const float* Wo = (const float*)d_in[5];   // [1024,1024]
    const float* bo = (const float*)d_in[6];   // [1024]
    float* out = (float*)d_out;                // [4,4096,1024] fp32

    short* wsS = (short*)d_ws;
    short* uv  = wsS;                          // 16384*2048
    short* xb  = uv + (size_t)16384 * 2048;    // 16384*1024 (later: yb)
    short* Wib = xb + (size_t)16384 * 1024;    // 2048*1024
    short* Wob = Wib + (size_t)2048 * 1024;    // 1024*1024

    dim3 blk(256);
    dim3 blkG(512);

    // one fused bf16 conversion pass (x, Wi, Wo)
    constexpr int nCvt = (16384 * 1024 + 2048 * 1024 + 1024 * 1024) / 8;
    cvt_all<<<(nCvt + 255) / 256, blk, 0, stream>>>(x, Wi, Wo, xb, Wib, Wob);

    // GEMM1: uv = xb @ Wib^T + bi   (M=16384, N=2048, K=1024), bf16 out
    dim3 g1(2048 / 256, 16384 / 256);          // (8, 64) = 512 blocks
    gemm_bt<false><<<g1, blkG, 0, stream>>>(xb, Wib, bi, uv, 1024, 1024, 2048);

    // conv + silu gate -> yb (reuses xb region; xb dead after GEMM1)
    conv_gate<<<(16384 * 128) / 256, blk, 0, stream>>>(uv, Wc, bc, xb);

    // GEMM2: out = yb @ Wob^T + bo  (M=16384, N=1024, K=1024), fp32 out
    dim3 g2(1024 / 256, 16384 / 256);          // (4, 64) = 256 blocks
    gemm_bt<true><<<g2, blkG, 0, stream>>>(xb, Wob, bo, out, 1024, 1024, 1024);
}

// Round 2
// 288.182 us; speedup vs baseline: 1.0787x; 1.0787x over previous
//
#include <hip/hip_runtime.h>
#include <math.h>

// MambaBlock, fp32 in/out, bf16 MFMA compute.
// uv = x @ Wi^T + bi ; u,v = split(uv) ; y = silu(dwconv3(v)+bc)*u ; out = y @ Wo^T + bo
// B=4, L=4096, D=1024 -> M = 16384 rows; GEMM1 N=2048, GEMM2 N=1024, K=1024.
//
// GEMM v3 (phase-split): 256x256 tile, BK=32, 512 threads (8 waves, 2M x 4N),
// ring of 4 LDS slots (128 KiB), prefetch depth 3 K-tiles, counted vmcnt(8).
// Each K-tile = 2 phases; phase 0 computes acc[0..3][*] (16 MFMA), phase 1
// computes acc[4..7][*].  Disjoint acc + fresh fragment regs per phase =>
// the MFMA pipe tail overlaps the next phase's ds_read/stage (the r1 version
// reused one fragment set per monolithic 32-MFMA tile, forcing WAR
// serialization -> 25% MfmaUtil).  B-frags read once per tile, held in regs.
// Stage is issued AFTER a barrier => ring slot (t+3)&3 is provably free
// (its last reader drained lgkmcnt before reaching that barrier).
//
// LDS swizzle (64B rows, 4x16B groups): logical group g of row r stored at
// physical g ^ ((r>>1)&3); staging pre-swizzles the GLOBAL source address
// (linear LDS dest for global_load_lds), ds_read applies the same XOR.

typedef __attribute__((ext_vector_type(8))) short short8;
typedef __attribute__((ext_vector_type(4))) float floatx4;

__device__ __forceinline__ float b2f(short s) {
    unsigned int u = ((unsigned int)(unsigned short)s) << 16;
    float f;
    __builtin_memcpy(&f, &u, 4);
    return f;
}

__device__ __forceinline__ short f2b(float f) {
    unsigned int u;
    __builtin_memcpy(&u, &f, 4);
    u += 0x7fffu + ((u >> 16) & 1u);   // round-to-nearest-even
    return (short)(u >> 16);
}

// async 16B/lane global->LDS; LDS dest = wave-uniform base + lane*16B.
__device__ __forceinline__ void gl_lds16(const short* g, short* l) {
    __builtin_amdgcn_global_load_lds(
        (const __attribute__((address_space(1))) unsigned int*)g,
        (__attribute__((address_space(3))) unsigned int*)l,
        16, 0, 0);
}

// single fp32->bf16 conversion pass over x, Wi, Wo (8 elems/thread)
__global__ __launch_bounds__(256) void cvt_all(
    const float* __restrict__ x, const float* __restrict__ Wi,
    const float* __restrict__ Wo, short* __restrict__ xb,
    short* __restrict__ Wib, short* __restrict__ Wob)
{
    constexpr int n1 = 16384 * 1024 / 8;
    constexpr int n2 = 2048 * 1024 / 8;
    constexpr int n3 = 1024 * 1024 / 8;
    int i = blockIdx.x * 256 + threadIdx.x;
    const float* src;
    short* dst;
    int j;
    if (i < n1)           { src = x;  dst = xb;  j = i; }
    else if (i < n1 + n2) { src = Wi; dst = Wib; j = i - n1; }
    else if (i < n1 + n2 + n3) { src = Wo; dst = Wob; j = i - n1 - n2; }
    else return;
    float4 a = ((const float4*)src)[2 * j];
    float4 b = ((const float4*)src)[2 * j + 1];
    short8 o;
    o[0] = f2b(a.x); o[1] = f2b(a.y); o[2] = f2b(a.z); o[3] = f2b(a.w);
    o[4] = f2b(b.x); o[5] = f2b(b.y); o[6] = f2b(b.z); o[7] = f2b(b.w);
    ((short8*)dst)[j] = o;
}

// One K-tile, two quadrant phases.  WAIT is the vmcnt immediate string for
// this tile; ST = tile index to stage (-1 = none); SLOT compile-time const.
#define GB_TILE(SLOT, WAIT, ST)                                              \
  {                                                                          \
    asm volatile(WAIT ::: "memory");                                         \
    __builtin_amdgcn_s_barrier();                                            \
    asm volatile("" ::: "memory");                                           \
    if ((ST) >= 0) {                                                         \
        gl_lds16(gA + (size_t)(ST) * 32, lA0 + ((ST) & 3) * 8192);           \
        gl_lds16(gA + (size_t)(ST) * 32 + (size_t)16 * lda,                  \
                 lA0 + ((ST) & 3) * 8192 + 512);                             \
    }                                                                        \
    const short* Ab = &As[(SLOT) * 8192];                                    \
    const short* Bb = &Bs[(SLOT) * 8192];                                    \
    short8 av0[4], av1[4], bvv[4];                                           \
    _Pragma("unroll") for (int ni = 0; ni < 4; ni++)                         \
        bvv[ni] = *(const short8*)&Bb[bBase + ni * 512];                     \
    _Pragma("unroll") for (int mi = 0; mi < 4; mi++)                         \
        av0[mi] = *(const short8*)&Ab[aBase + mi * 512];                     \
    asm volatile("s_waitcnt lgkmcnt(0)" ::: "memory");                       \
    __builtin_amdgcn_sched_barrier(0);                                       \
    __builtin_amdgcn_s_setprio(1);                                           \
    _Pragma("unroll") for (int mi = 0; mi < 4; mi++)                         \
      _Pragma("unroll") for (int ni = 0; ni < 4; ni++)                       \
        acc[mi][ni] = __builtin_amdgcn_mfma_f32_16x16x32_bf16(               \
            av0[mi], bvv[ni], acc[mi][ni], 0, 0, 0);                         \
    __builtin_amdgcn_s_setprio(0);                                           \
    __builtin_amdgcn_s_barrier();                                            \
    asm volatile("" ::: "memory");                                           \
    if ((ST) >= 0) {                                                         \
        gl_lds16(gB + (size_t)(ST) * 32, lB0 + ((ST) & 3) * 8192);           \
        gl_lds16(gB + (size_t)(ST) * 32 + (size_t)16 * ldb,                  \
                 lB0 + ((ST) & 3) * 8192 + 512);                             \
    }                                                                        \
    _Pragma("unroll") for (int mi = 0; mi < 4; mi++)                         \
        av1[mi] = *(const short8*)&Ab[aBase + (4 + mi) * 512];               \
    asm volatile("s_waitcnt lgkmcnt(0)" ::: "memory");                       \
    __builtin_amdgcn_sched_barrier(0);                                       \
    __builtin_amdgcn_s_setprio(1);                                           \
    _Pragma("unroll") for (int mi = 0; mi < 4; mi++)                         \
      _Pragma("unroll") for (int ni = 0; ni < 4; ni++)                       \
        acc[4 + mi][ni] = __builtin_amdgcn_mfma_f32_16x16x32_bf16(           \
            av1[mi], bvv[ni], acc[4 + mi][ni], 0, 0, 0);                     \
    __builtin_amdgcn_s_setprio(0);                                           \
  }

// C[m][n] = sum_k A[m][k]*B[n][k] + bias[n].  A,B bf16 (B row-major [N][K]).
// OUTF32: C fp32, else C bf16.  256x256 tile, BK=32, phase-split pipeline.
template <bool OUTF32>
__global__ __launch_bounds__(512, 2) void gemm_bt(
    const short* __restrict__ A, const short* __restrict__ B,
    const float* __restrict__ bias, void* __restrict__ Cv,
    int lda, int ldb, int ldc)
{
    // ring of 4 slots; each slot 256 rows x 32 shorts = 16 KB per operand.
    __shared__ __attribute__((aligned(16))) short As[4 * 8192];
    __shared__ __attribute__((aligned(16))) short Bs[4 * 8192];

    const int tid  = threadIdx.x;
    const int wave = tid >> 6;                 // 0..7
    const int lane = tid & 63;

    // T1: bijective XCD swizzle (nwg % 8 == 0 for both GEMMs) -> each XCD
    // owns a contiguous M-chunk; B panels stream, A chunk stays L2-hot.
    const int nwg = gridDim.x * gridDim.y;
    const int f   = blockIdx.y * gridDim.x + blockIdx.x;
    const int nf  = (f & 7) * (nwg >> 3) + (f >> 3);
    const int mBase = (nf / gridDim.x) * 256;
    const int nBase = (nf % gridDim.x) * 256;

    floatx4 acc[8][4];
#pragma unroll
    for (int i = 0; i < 8; i++)
#pragma unroll
        for (int j = 0; j < 4; j++) acc[i][j] = {0.f, 0.f, 0.f, 0.f};

    // staging: wave w owns rows [32w, 32w+32) of A and B.  Per operand per
    // tile: 2 instrs (each = 16 rows x 64B = 1KB/wave).  lane -> row
    // (lane>>2), dest 16B group (lane&3); source group = dest ^ ((row>>1)&3).
    const int srow = lane >> 2;                // 0..15
    const int sg   = ((lane & 3) ^ ((srow >> 1) & 3)) * 8;
    const short* gA = A + (size_t)(mBase + wave * 32 + srow) * lda + sg;
    const short* gB = B + (size_t)(nBase + wave * 32 + srow) * ldb + sg;
    short* lA0 = &As[wave * 1024];             // rows 32w.. of slot 0
    short* lB0 = &Bs[wave * 1024];

    // fragments: wave (wm = wave>>2, wn = wave&3) owns a 128x64 C panel.
    const int fRow = lane & 15;
    const int lg   = lane >> 4;                // k-group 0..3
    const int pg8  = (lg ^ ((fRow >> 1) & 3)) * 8;
    const int mq   = (wave >> 2) * 128;
    const int nq   = (wave & 3) * 64;
    const int aBase = (mq + fRow) * 32 + pg8;
    const int bBase = (nq + fRow) * 32 + pg8;

    // prologue: tiles 0..2 in flight (12 loads/thread)
#pragma unroll
    for (int p = 0; p < 3; p++) {
        gl_lds16(gA + (size_t)p * 32, lA0 + p * 8192);
        gl_lds16(gA + (size_t)p * 32 + (size_t)16 * lda, lA0 + p * 8192 + 512);
        gl_lds16(gB + (size_t)p * 32, lB0 + p * 8192);
        gl_lds16(gB + (size_t)p * 32 + (size_t)16 * ldb, lB0 + p * 8192 + 512);
    }

    // main: t = 0..27 (slots cycle 0..3), stage tile t+3, keep 8+ loads in
    // flight.  Tail: t=28 stages 31; t=29..31 drain 8 -> 4 -> 0.
    for (int tb = 0; tb < 28; tb += 4) {
        GB_TILE(0, "s_waitcnt vmcnt(8)", tb + 3)
        GB_TILE(1, "s_waitcnt vmcnt(8)", tb + 4)
        GB_TILE(2, "s_waitcnt vmcnt(8)", tb + 5)
        GB_TILE(3, "s_waitcnt vmcnt(8)", tb + 6)
    }
    GB_TILE(0, "s_waitcnt vmcnt(8)", 31)
    GB_TILE(1, "s_waitcnt vmcnt(8)", -1)
    GB_TILE(2, "s_waitcnt vmcnt(4)", -1)
    GB_TILE(3, "s_waitcnt vmcnt(0)", -1)

    // C/D layout: col = lane&15, row = (lane>>4)*4 + reg   [m89/m91-verified]
    const int colq = lane & 15;
    const int rowq = lg * 4;
#pragma unroll
    for (int ni = 0; ni < 4; ni++) {
        const int col = nBase + nq + ni * 16 + colq;
        const float bvv2 = bias[col];
#pragma unroll
        for (int mi = 0; mi < 8; mi++) {
            const int row = mBase + mq + mi * 16 + rowq;
#pragma unroll
            for (int r = 0; r < 4; r++) {
                float v = acc[mi][ni][r] + bvv2;
                if (OUTF32)
                    ((float*)Cv)[(size_t)(row + r) * ldc + col] = v;
                else
                    ((short*)Cv)[(size_t)(row + r) * ldc + col] = f2b(v);
            }
        }
    }
}

// y[m][d] = silu( v[m-1]*w0 + v[m]*w1 + v[m+1]*w2 + bc ) * u[m][d]
// uv bf16 [16384][2048] (u cols 0..1023, v cols 1024..2047); Wc/bc fp32;
// y written bf16 to yb [16384][1024]. 8 channels per thread.
__global__ __launch_bounds__(256) void conv_gate(
    const short* __restrict__ uv, const float* __restrict__ Wc,
    const float* __restrict__ bc, short* __restrict__ yb)
{
    const int idx = blockIdx.x * 256 + threadIdx.x;
    const int d8 = idx & 127;
    const int m  = idx >> 7;
    const int l  = m & 4095;             // L = 4096, zero-pad at batch edges
    const int d  = d8 * 8;

    float w[24];
#pragma unroll
    for (int q = 0; q < 6; q++)
        *(float4*)&w[q * 4] = ((const float4*)(Wc + d * 3))[q];
    float bcv[8];
    *(float4*)&bcv[0] = ((const float4*)(bc + d))[0];
    *(float4*)&bcv[4] = ((const float4*)(bc + d))[1];

    const size_t rowu = (size_t)m * 2048 + d;
    const size_t rowv = rowu + 1024;

    const short8 z = {0, 0, 0, 0, 0, 0, 0, 0};
    const short8 us = *(const short8*)(uv + rowu);
    const short8 vc = *(const short8*)(uv + rowv);
    const short8 vm = (l > 0)    ? *(const short8*)(uv + rowv - 2048) : z;
    const short8 vp = (l < 4095) ? *(const short8*)(uv + rowv + 2048) : z;

    short8 outv;
#pragma unroll
    for (int j = 0; j < 8; j++) {
        float y = b2f(vm[j]) * w[j * 3 + 0]
                + b2f(vc[j]) * w[j * 3 + 1]
                + b2f(vp[j]) * w[j * 3 + 2]
                + bcv[j];
        float sil = y / (1.0f + expf(-y));
        outv[j] = f2b(sil * b2f(us[j]));
    }
    *(short8*)(yb + (size_t)m * 1024 + d) = outv;
}

extern "C" void kernel_launch(void* const* d_in, const int* in_sizes, int n_in,
                              void* d_out, int out_size, void* d_ws, size_t ws_size,
                              hipStream_t stream)
{
    const float* x  = (const float*)d_in[0];   // [4,4096,1024]
    const float* Wi = (const float*)d_in[1];   // [2048,1024]
    const float* bi = (const float*)d_in[2];   // [2048]
    const float* Wc = (const float*)d_in[3];   // [1024,1,3]
    const float* bc = (const float*)d_in[4];   // [1024]
    const float* Wo = (const float*)d_in[5];   // [1024,1024]
    const float* bo = (const float*)d_in[6];   // [1024]
    float* out = (float*)d_out;                // [4,4096,1024] fp32

    short* wsS = (short*)d_ws;
    short* uv  = wsS;                          // 16384*2048
    short* xb  = uv + (size_t)16384 * 2048;    // 16384*1024 (later: yb)
    short* Wib = xb + (size_t)16384 * 1024;    // 2048*1024
    short* Wob = Wib + (size_t)2048 * 1024;    // 1024*1024

    dim3 blk(256);
    dim3 blkG(512);

    // one fused bf16 conversion pass (x, Wi, Wo)
    constexpr int nCvt = (16384 * 1024 + 2048 * 1024 + 1024 * 1024) / 8;
    cvt_all<<<(nCvt + 255) / 256, blk, 0, stream>>>(x, Wi, Wo, xb, Wib, Wob);

    // GEMM1: uv = xb @ Wib^T + bi   (M=16384, N=2048, K=1024), bf16 out
    dim3 g1(2048 / 256, 16384 / 256);          // (8, 64) = 512 blocks
    gemm_bt<false><<<g1, blkG, 0, stream>>>(xb, Wib, bi, uv, 1024, 1024, 2048);

    // conv + silu gate -> yb (reuses xb region; xb dead after GEMM1)
    conv_gate<<<(16384 * 128) / 256, blk, 0, stream>>>(uv, Wc, bc, xb);

    // GEMM2: out = yb @ Wob^T + bo  (M=16384, N=1024, K=1024), fp32 out
    dim3 g2(1024 / 256, 16384 / 256);          // (4, 64) = 256 blocks
    gemm_bt<true><<<g2, blkG, 0, stream>>>(xb, Wob, bo, out, 1024, 1024, 1024);
}